// Round 6
// baseline (146.897 us; speedup 1.0000x reference)
//
#include <hip/hip_runtime.h>

// Problem constants
#define H_  1024
#define W_  1024
#define B_  4
#define GH  16
#define GW  16
#define GD  8
#define NC  12
#define CELLF (GD * NC)      // 96 floats per (y,x) grid cell
#define YROWF (GW * CELLF)   // 1536 floats per grid y-row

// Tiling: block (64,4) = 256 threads; tile 64 wide x 8 tall; 2 rows/thread.
// This is the ROUND-0 passing structure with ONE change: the image LDS
// staging is deleted; the conv reads its 4x9 neighborhood directly from
// global (L1-cached 3x overlap). Tables/epilogue identical to round 0.
#define TW 64
#define TH 8

typedef _Float16 h2 __attribute__((ext_vector_type(2)));

__device__ __forceinline__ h2 u2h(unsigned int u) { return __builtin_bit_cast(h2, u); }

// 12-byte pixel load (global_load_dwordx3), optionally zero-padded OOB.
template<bool G>
__device__ __forceinline__ void load3g(const float* base, int yy, int xx, float* d) {
    if constexpr (!G) {
        __builtin_memcpy(d, base + (yy * W_ + xx) * 3, 12);
    } else {
        d[0] = 0.f; d[1] = 0.f; d[2] = 0.f;
        if (((unsigned)yy < (unsigned)H_) && ((unsigned)xx < (unsigned)W_))
            __builtin_memcpy(d, base + (yy * W_ + xx) * 3, 12);
    }
}

// One image row, cols x-1..x+1 (9 floats: 3 px * 3 ch) into d.
template<bool G>
__device__ __forceinline__ void loadrow9(const float* base, int ry, int x, float* d) {
    load3g<G>(base, ry, x - 1, d + 0);
    load3g<G>(base, ry, x,     d + 3);
    load3g<G>(base, ry, x + 1, d + 6);
}

// 3x3 conv for one output row from rows a,b,c (kh=0,1,2). Same math as round 0.
__device__ __forceinline__ void conv3r(const float* a, const float* b, const float* c,
                                       float* acc, const float* wgt,
                                       float bias0, float bias1, float bias2) {
    acc[0] = bias0; acc[1] = bias1; acc[2] = bias2;
    const float* rows[3] = {a, b, c};
    #pragma unroll
    for (int kh = 0; kh < 3; ++kh)
        #pragma unroll
        for (int kw = 0; kw < 3; ++kw)
            #pragma unroll
            for (int ci = 0; ci < 3; ++ci) {
                float v = rows[kh][kw * 3 + ci];
                const float* wb = wgt + ((kh * 3 + kw) * 3 + ci) * 3;
                acc[0] += v * wb[0];
                acc[1] += v * wb[1];
                acc[2] += v * wb[2];
            }
}

__global__ __launch_bounds__(256, 8)
void fused_conv_slice(const float* __restrict__ grid,
                      const float* __restrict__ guide,
                      const float* __restrict__ image,
                      const float* __restrict__ conv_w,
                      const float* __restrict__ conv_b,
                      float* __restrict__ out)
{
    // f16 y-lerped tables, split for bank spread (identical to round 0):
    //   T128: coeffs 0..7 of corner (cell s, z); T64: coeffs 8..11
    __shared__ uint4 s_t128[TH][3 * GD];           // 3072 B
    __shared__ uint2 s_t64[TH][3 * GD];            // 1536 B  (4608 B total)

    const int tx  = threadIdx.x;   // 0..63 (one wave per tyq)
    const int tyq = threadIdx.y;   // 0..3
    const int bx  = blockIdx.x;
    const int by  = blockIdx.y;
    const int b   = blockIdx.z;
    const int x0 = bx * TW;
    const int y0 = by * TH;
    const int tid = tyq * 64 + tx;
    const float* ib = image + b * (H_ * W_ * 3);

    // ---- cooperative fill of the 8 row-tables (f16, split layout) — round-0 verbatim ----
    int cells[3];
    cells[0] = max(bx - 1, 0);
    cells[1] = bx;
    cells[2] = min(bx + 1, GW - 1);
    const float* gB = grid + b * (GH * GW * GD * NC);
    {
        int rr = tid >> 5;          // table row 0..7 (32 threads each)
        int le = tid & 31;
        int y  = y0 + rr;
        float gyf = (y + 0.5f) * (1.0f / 64.0f) - 0.5f;
        float fyf = floorf(gyf);
        float tyw = gyf - fyf;
        int iy = (int)fyf;
        int yi0 = min(max(iy, 0), GH - 1);
        int yi1 = min(max(iy + 1, 0), GH - 1);
        float wy0 = 1.0f - tyw, wy1 = tyw;
        const float4* G0 = (const float4*)(gB + yi0 * YROWF);
        const float4* G1 = (const float4*)(gB + yi1 * YROWF);
        #pragma unroll
        for (int k = 0; k < 3; ++k) {
            int e = le + k * 32;                 // 72 float4 per row-table
            if (e < 72) {
                int s  = (e >= 48) ? 2 : ((e >= 24) ? 1 : 0);   // cell slot
                int re = e - s * 24;             // 0..23 within cell
                int z  = re / 3;                 // 0..7
                int c4 = re - z * 3;             // float4 index within corner (0..2)
                int off = cells[s] * 24 + re;
                float4 v0 = G0[off], v1 = G1[off];
                h2 p0, p1;
                p0.x = (_Float16)(wy0 * v0.x + wy1 * v1.x);
                p0.y = (_Float16)(wy0 * v0.y + wy1 * v1.y);
                p1.x = (_Float16)(wy0 * v0.z + wy1 * v1.z);
                p1.y = (_Float16)(wy0 * v0.w + wy1 * v1.w);
                uint2 u;
                u.x = __builtin_bit_cast(unsigned int, p0);
                u.y = __builtin_bit_cast(unsigned int, p1);
                int ci = s * GD + z;
                unsigned short* dst = (c4 == 2)
                    ? (unsigned short*)&s_t64[rr][ci]
                    : (unsigned short*)&s_t128[rr][ci] + c4 * 4;
                *(uint2*)dst = u;
            }
        }
    }

    // ---- guide prefetch (round-0 verbatim) ----
    const int x = x0 + tx;
    const int lr = tyq * 2;
    const int guidebase = b * (H_ * W_);
    float g2[2];
    #pragma unroll
    for (int j = 0; j < 2; ++j)
        g2[j] = guide[guidebase + (y0 + lr + j) * W_ + x];

    // ---- conv weights: uniform reads -> SGPRs (round-0 verbatim) ----
    float wgt[81];
    #pragma unroll
    for (int i = 0; i < 81; ++i) wgt[i] = conv_w[i];
    float bias0 = conv_b[0], bias1 = conv_b[1], bias2 = conv_b[2];

    // ---- conv: direct-from-global (THE one change vs round 0) ----
    // This thread's 2 output rows R0, R0+1 need input rows R0-1..R0+2.
    const int R0 = y0 + lr;
    float ra[9], rb[9], rc[9], rd[9];
    const bool edge = (bx == 0) | (bx == (W_ / TW - 1)) |
                      (by == 0) | (by == (H_ / TH - 1));
    if (!edge) {
        loadrow9<false>(ib, R0 - 1, x, ra);
        loadrow9<false>(ib, R0 + 0, x, rb);
        loadrow9<false>(ib, R0 + 1, x, rc);
        loadrow9<false>(ib, R0 + 2, x, rd);
    } else {
        loadrow9<true>(ib, R0 - 1, x, ra);
        loadrow9<true>(ib, R0 + 0, x, rb);
        loadrow9<true>(ib, R0 + 1, x, rc);
        loadrow9<true>(ib, R0 + 2, x, rd);
    }
    float acc2r[2][3];
    conv3r(ra, rb, rc, acc2r[0], wgt, bias0, bias1, bias2);
    conv3r(rb, rc, rd, acc2r[1], wgt, bias0, bias1, bias2);

    __syncthreads();  // tables visible; the ONLY barrier

    // ---- per-thread x-interp setup (round-0 verbatim) ----
    float gxf = (x + 0.5f) * (1.0f / 64.0f) - 0.5f;
    float fxf = floorf(gxf);
    float txw = gxf - fxf;
    float wxa = 1.0f - txw, wxb = txw;
    int s0 = (int)fxf - (bx - 1);   // table x-slot of left corner: 0 or 1

    const int outbase = b * (H_ * W_ * 3);

    #pragma unroll
    for (int j = 0; j < 2; ++j) {
        int y = y0 + lr + j;
        const uint4* T128 = &s_t128[lr + j][0];
        const uint2* T64  = &s_t64[lr + j][0];

        float gzf = g2[j] * 8.0f - 0.5f;
        float fzf = floorf(gzf);
        float tz = gzf - fzf;
        int iz = (int)fzf;                    // -1..7
        int zb = min(max(iz, 0), GD - 2);     // contiguous z-pair base
        float wA = (iz < 0) ? 1.0f : ((iz > GD - 2) ? 0.0f : (1.0f - tz));
        float wB = 1.0f - wA;

        float m0 = wxa * wA, m1 = wxa * wB, m2 = wxb * wA, m3 = wxb * wB;
        h2 m0h = {(_Float16)m0, (_Float16)m0};
        h2 m1h = {(_Float16)m1, (_Float16)m1};
        h2 m2h = {(_Float16)m2, (_Float16)m2};
        h2 m3h = {(_Float16)m3, (_Float16)m3};

        // corners: A=(s0,zb) B=(s0,zb+1) C=(s0+1,zb) D=(s0+1,zb+1)
        int ci0 = s0 * GD + zb;
        uint4 Alo = T128[ci0];          uint2 Ahi = T64[ci0];
        uint4 Blo = T128[ci0 + 1];      uint2 Bhi = T64[ci0 + 1];
        uint4 Clo = T128[ci0 + GD];     uint2 Chi = T64[ci0 + GD];
        uint4 Dlo = T128[ci0 + GD + 1]; uint2 Dhi = T64[ci0 + GD + 1];

        h2 A[6]  = {u2h(Alo.x), u2h(Alo.y), u2h(Alo.z), u2h(Alo.w), u2h(Ahi.x), u2h(Ahi.y)};
        h2 Bv[6] = {u2h(Blo.x), u2h(Blo.y), u2h(Blo.z), u2h(Blo.w), u2h(Bhi.x), u2h(Bhi.y)};
        h2 Cv[6] = {u2h(Clo.x), u2h(Clo.y), u2h(Clo.z), u2h(Clo.w), u2h(Chi.x), u2h(Chi.y)};
        h2 Dv[6] = {u2h(Dlo.x), u2h(Dlo.y), u2h(Dlo.z), u2h(Dlo.w), u2h(Dhi.x), u2h(Dhi.y)};

        // packed-f16 4-corner lerp
        h2 c[6];
        #pragma unroll
        for (int k = 0; k < 6; ++k)
            c[k] = __builtin_elementwise_fma(A[k], m0h,
                   __builtin_elementwise_fma(Bv[k], m1h,
                   __builtin_elementwise_fma(Cv[k], m2h, Dv[k] * m3h)));

        // apply: out_o = c[2o]·{a0,a1} + c[2o+1]·{a2,1}  (fdot2, f32 accumulate)
        float a0 = acc2r[j][0], a1 = acc2r[j][1], a2 = acc2r[j][2];
        h2 q01 = {(_Float16)a0, (_Float16)a1};
        h2 q21 = {(_Float16)a2, (_Float16)1.0f};

        int oidx = outbase + (y * W_ + x) * 3;
        #pragma unroll
        for (int o3 = 0; o3 < 3; ++o3) {
            float t = __builtin_amdgcn_fdot2(c[2 * o3 + 1], q21, 0.0f, false);
            out[oidx + o3] = __builtin_amdgcn_fdot2(c[2 * o3], q01, t, false);
        }
    }
}

extern "C" void kernel_launch(void* const* d_in, const int* in_sizes, int n_in,
                              void* d_out, int out_size, void* d_ws, size_t ws_size,
                              hipStream_t stream) {
    const float* grid   = (const float*)d_in[0];
    const float* guide  = (const float*)d_in[1];
    const float* image  = (const float*)d_in[2];
    const float* conv_w = (const float*)d_in[3];
    const float* conv_b = (const float*)d_in[4];
    float* out = (float*)d_out;

    dim3 block(64, 4, 1);
    dim3 grid_dim(W_ / TW, H_ / TH, B_);  // (16, 128, 4)
    fused_conv_slice<<<grid_dim, block, 0, stream>>>(grid, guide, image, conv_w, conv_b, out);
}

// Round 8
// 137.227 us; speedup vs baseline: 1.0705x; 1.0705x over previous
//
#include <hip/hip_runtime.h>

// Problem constants
#define H_  1024
#define W_  1024
#define B_  4
#define GH  16
#define GW  16
#define GD  8
#define NC  12
#define CELLF (GD * NC)      // 96 floats per (y,x) grid cell
#define YROWF (GW * CELLF)   // 1536 floats per grid y-row

// Block (64,4); tile 64 wide x 8 tall; 2 output rows per thread.
// BARRIER-FREE: each wave owns a private image slice (4 input rows x 66 px)
// staged via width-4 global_load_lds DMA, and its own 2 table rows
// (the r0 fill is wave-local by construction). One per-wave waitcnt fence.
#define TW 64
#define TH 8
#define ROWF 198             // floats per staged row (66 px * 3 ch)
#define WVALID (4 * ROWF)    // 792 valid floats per wave
#define WFLOATS (13 * 64)    // 832 slots (13 DMA instr x 64 lanes)

typedef _Float16 h2 __attribute__((ext_vector_type(2)));

__device__ __forceinline__ h2 u2h(unsigned int u) { return __builtin_bit_cast(h2, u); }

// global -> LDS DMA, 4 bytes/lane (HW-verified width). dest = uniform base + lane*4.
__device__ __forceinline__ void gload_lds4(const float* g, float* l) {
    auto gp = (const __attribute__((address_space(1))) float*)g;
    auto lp = (__attribute__((address_space(3))) float*)l;
    __builtin_amdgcn_global_load_lds(gp, lp, 4, 0, 0);
}

// 3x3 conv for one output row from rows a,b,c (kh=0,1,2) — r0/r6 verbatim math.
__device__ __forceinline__ void conv3r(const float* a, const float* b, const float* c,
                                       float* acc, const float* wgt,
                                       float bias0, float bias1, float bias2) {
    acc[0] = bias0; acc[1] = bias1; acc[2] = bias2;
    const float* rows[3] = {a, b, c};
    #pragma unroll
    for (int kh = 0; kh < 3; ++kh)
        #pragma unroll
        for (int kw = 0; kw < 3; ++kw)
            #pragma unroll
            for (int ci = 0; ci < 3; ++ci) {
                float v = rows[kh][kw * 3 + ci];
                const float* wb = wgt + ((kh * 3 + kw) * 3 + ci) * 3;
                acc[0] += v * wb[0];
                acc[1] += v * wb[1];
                acc[2] += v * wb[2];
            }
}

__global__ __launch_bounds__(256, 8)
void fused_conv_slice(const float* __restrict__ grid,
                      const float* __restrict__ guide,
                      const float* __restrict__ image,
                      const float* __restrict__ conv_w,
                      const float* __restrict__ conv_b,
                      float* __restrict__ out)
{
    // Per-wave image slice: s_img[wave][f], f = r*198 + c*3 + ch (r=0..3, c=0..65).
    __shared__ float s_img[4][WFLOATS];            // 13312 B
    // f16 y-lerped tables, split layout (round-0 verbatim; wave-local rows)
    __shared__ uint4 s_t128[TH][3 * GD];           // 3072 B
    __shared__ uint2 s_t64[TH][3 * GD];            // 1536 B   (17920 B total)

    const int tx  = threadIdx.x;   // 0..63 (one wave per tyq)
    const int tyq = threadIdx.y;   // 0..3
    const int bx  = blockIdx.x;
    const int by  = blockIdx.y;
    const int b   = blockIdx.z;
    const int x0 = bx * TW;
    const int y0 = by * TH;
    const int tid = tyq * 64 + tx;
    const int lr = tyq * 2;        // this wave's first output row offset
    const float* ib = image + b * (H_ * W_ * 3);

    // ---- cooperative fill of the 8 row-tables (f16, split layout) — round-0 verbatim.
    // Wave tyq fills rows {2tyq, 2tyq+1} = exactly the rows it reads: wave-local.
    int cells[3];
    cells[0] = max(bx - 1, 0);
    cells[1] = bx;
    cells[2] = min(bx + 1, GW - 1);
    const float* gB = grid + b * (GH * GW * GD * NC);
    {
        int rr = tid >> 5;          // table row 0..7 (32 threads each)
        int le = tid & 31;
        int y  = y0 + rr;
        float gyf = (y + 0.5f) * (1.0f / 64.0f) - 0.5f;
        float fyf = floorf(gyf);
        float tyw = gyf - fyf;
        int iy = (int)fyf;
        int yi0 = min(max(iy, 0), GH - 1);
        int yi1 = min(max(iy + 1, 0), GH - 1);
        float wy0 = 1.0f - tyw, wy1 = tyw;
        const float4* G0 = (const float4*)(gB + yi0 * YROWF);
        const float4* G1 = (const float4*)(gB + yi1 * YROWF);
        #pragma unroll
        for (int k = 0; k < 3; ++k) {
            int e = le + k * 32;                 // 72 float4 per row-table
            if (e < 72) {
                int s  = (e >= 48) ? 2 : ((e >= 24) ? 1 : 0);   // cell slot
                int re = e - s * 24;             // 0..23 within cell
                int z  = re / 3;                 // 0..7
                int c4 = re - z * 3;             // float4 index within corner (0..2)
                int off = cells[s] * 24 + re;
                float4 v0 = G0[off], v1 = G1[off];
                h2 p0, p1;
                p0.x = (_Float16)(wy0 * v0.x + wy1 * v1.x);
                p0.y = (_Float16)(wy0 * v0.y + wy1 * v1.y);
                p1.x = (_Float16)(wy0 * v0.z + wy1 * v1.z);
                p1.y = (_Float16)(wy0 * v0.w + wy1 * v1.w);
                uint2 u;
                u.x = __builtin_bit_cast(unsigned int, p0);
                u.y = __builtin_bit_cast(unsigned int, p1);
                int ci = s * GD + z;
                unsigned short* dst = (c4 == 2)
                    ? (unsigned short*)&s_t64[rr][ci]
                    : (unsigned short*)&s_t128[rr][ci] + c4 * 4;
                *(uint2*)dst = u;
            }
        }
    }

    // ---- per-wave image staging: input rows (y0+lr-1 .. y0+lr+2), cols x0-1..x0+64 ----
    const int wr0 = y0 + lr - 1;                  // first staged input row
    const bool edge = (bx == 0) | (bx == (W_ / TW - 1)) |
                      (by == 0) | (by == (H_ / TH - 1));
    if (!edge) {
        // DMA path: 13 width-4 global_load_lds per wave, zero payload VGPRs.
        #pragma unroll
        for (int i = 0; i < 13; ++i) {
            int f  = i * 64 + tx;
            int fe = min(f, WVALID - 1);          // overshoot lanes dup (slots never read)
            int r  = fe / ROWF;                   // 0..3
            int off = fe - r * ROWF;
            const float* src = ib + ((wr0 + r) * W_ + (x0 - 1)) * 3 + off;
            gload_lds4(src, &s_img[tyq][i * 64]);
        }
    } else {
        // Guarded per-wave reg-staged path with zero padding (border blocks, ~25%).
        #pragma unroll
        for (int i = 0; i < 5; ++i) {
            int p = i * 64 + tx;                  // px index 0..263 (4 rows x 66)
            if (p < 264) {
                int r = p / 66;
                int c = p - r * 66;
                int yy = wr0 + r;
                int xx = x0 - 1 + c;
                float v[3] = {0.f, 0.f, 0.f};
                if (((unsigned)yy < (unsigned)H_) && ((unsigned)xx < (unsigned)W_))
                    __builtin_memcpy(v, ib + (yy * W_ + xx) * 3, 12);
                float* d = &s_img[tyq][r * ROWF + c * 3];
                d[0] = v[0]; d[1] = v[1]; d[2] = v[2];
            }
        }
    }

    // ---- guide prefetch ----
    const int x = x0 + tx;
    const int guidebase = b * (H_ * W_);
    float g2[2];
    #pragma unroll
    for (int j = 0; j < 2; ++j)
        g2[j] = guide[guidebase + (y0 + lr + j) * W_ + x];

    // ---- conv weights: uniform reads -> SGPRs ----
    float wgt[81];
    #pragma unroll
    for (int i = 0; i < 81; ++i) wgt[i] = conv_w[i];
    float bias0 = conv_b[0], bias1 = conv_b[1], bias2 = conv_b[2];

    // ---- per-wave fence: NO __syncthreads in this kernel.
    // Drains this wave's DMAs (vmcnt) + its table ds_writes (lgkmcnt);
    // sched_barrier stops hipcc reordering consumers above it (rule #18).
    __asm__ __volatile__("s_waitcnt vmcnt(0) lgkmcnt(0)" ::: "memory");
    __builtin_amdgcn_sched_barrier(0);

    // ---- conv for this thread's 2 rows, f32 from the wave's LDS slice ----
    auto ldr9 = [&](int r, float* d) {
        __builtin_memcpy(d, &s_img[tyq][r * ROWF + tx * 3], 36);
    };
    float ra[9], rb[9], rc[9];
    float acc2r[2][3];
    ldr9(0, ra);
    ldr9(1, rb);
    ldr9(2, rc);
    conv3r(ra, rb, rc, acc2r[0], wgt, bias0, bias1, bias2);
    ldr9(3, ra);
    conv3r(rb, rc, ra, acc2r[1], wgt, bias0, bias1, bias2);

    // ---- per-thread x-interp setup (round-0 verbatim) ----
    float gxf = (x + 0.5f) * (1.0f / 64.0f) - 0.5f;
    float fxf = floorf(gxf);
    float txw = gxf - fxf;
    float wxa = 1.0f - txw, wxb = txw;
    int s0 = (int)fxf - (bx - 1);   // table x-slot of left corner: 0 or 1

    const int outbase = b * (H_ * W_ * 3);

    #pragma unroll
    for (int j = 0; j < 2; ++j) {
        int y = y0 + lr + j;
        const uint4* T128 = &s_t128[lr + j][0];
        const uint2* T64  = &s_t64[lr + j][0];

        float gzf = g2[j] * 8.0f - 0.5f;
        float fzf = floorf(gzf);
        float tz = gzf - fzf;
        int iz = (int)fzf;                    // -1..7
        int zb = min(max(iz, 0), GD - 2);     // contiguous z-pair base
        float wA = (iz < 0) ? 1.0f : ((iz > GD - 2) ? 0.0f : (1.0f - tz));
        float wB = 1.0f - wA;

        float m0 = wxa * wA, m1 = wxa * wB, m2 = wxb * wA, m3 = wxb * wB;
        h2 m0h = {(_Float16)m0, (_Float16)m0};
        h2 m1h = {(_Float16)m1, (_Float16)m1};
        h2 m2h = {(_Float16)m2, (_Float16)m2};
        h2 m3h = {(_Float16)m3, (_Float16)m3};

        // corners: A=(s0,zb) B=(s0,zb+1) C=(s0+1,zb) D=(s0+1,zb+1)
        int ci0 = s0 * GD + zb;
        uint4 Alo = T128[ci0];          uint2 Ahi = T64[ci0];
        uint4 Blo = T128[ci0 + 1];      uint2 Bhi = T64[ci0 + 1];
        uint4 Clo = T128[ci0 + GD];     uint2 Chi = T64[ci0 + GD];
        uint4 Dlo = T128[ci0 + GD + 1]; uint2 Dhi = T64[ci0 + GD + 1];

        h2 A[6]  = {u2h(Alo.x), u2h(Alo.y), u2h(Alo.z), u2h(Alo.w), u2h(Ahi.x), u2h(Ahi.y)};
        h2 Bv[6] = {u2h(Blo.x), u2h(Blo.y), u2h(Blo.z), u2h(Blo.w), u2h(Bhi.x), u2h(Bhi.y)};
        h2 Cv[6] = {u2h(Clo.x), u2h(Clo.y), u2h(Clo.z), u2h(Clo.w), u2h(Chi.x), u2h(Chi.y)};
        h2 Dv[6] = {u2h(Dlo.x), u2h(Dlo.y), u2h(Dlo.z), u2h(Dlo.w), u2h(Dhi.x), u2h(Dhi.y)};

        // packed-f16 4-corner lerp
        h2 c[6];
        #pragma unroll
        for (int k = 0; k < 6; ++k)
            c[k] = __builtin_elementwise_fma(A[k], m0h,
                   __builtin_elementwise_fma(Bv[k], m1h,
                   __builtin_elementwise_fma(Cv[k], m2h, Dv[k] * m3h)));

        // apply: out_o = c[2o]·{a0,a1} + c[2o+1]·{a2,1}  (fdot2, f32 accumulate)
        float a0 = acc2r[j][0], a1 = acc2r[j][1], a2 = acc2r[j][2];
        h2 q01 = {(_Float16)a0, (_Float16)a1};
        h2 q21 = {(_Float16)a2, (_Float16)1.0f};

        int oidx = outbase + (y * W_ + x) * 3;
        #pragma unroll
        for (int o3 = 0; o3 < 3; ++o3) {
            float t = __builtin_amdgcn_fdot2(c[2 * o3 + 1], q21, 0.0f, false);
            out[oidx + o3] = __builtin_amdgcn_fdot2(c[2 * o3], q01, t, false);
        }
    }
}

extern "C" void kernel_launch(void* const* d_in, const int* in_sizes, int n_in,
                              void* d_out, int out_size, void* d_ws, size_t ws_size,
                              hipStream_t stream) {
    const float* grid   = (const float*)d_in[0];
    const float* guide  = (const float*)d_in[1];
    const float* image  = (const float*)d_in[2];
    const float* conv_w = (const float*)d_in[3];
    const float* conv_b = (const float*)d_in[4];
    float* out = (float*)d_out;

    dim3 block(64, 4, 1);
    dim3 grid_dim(W_ / TW, H_ / TH, B_);  // (16, 128, 4)
    fused_conv_slice<<<grid_dim, block, 0, stream>>>(grid, guide, image, conv_w, conv_b, out);
}

// Round 9
// 137.028 us; speedup vs baseline: 1.0720x; 1.0015x over previous
//
#include <hip/hip_runtime.h>

// Problem constants
#define H_  1024
#define W_  1024
#define B_  4
#define GH  16
#define GW  16
#define GD  8
#define NC  12
#define CELLF (GD * NC)      // 96 floats per (y,x) grid cell
#define YROWF (GW * CELLF)   // 1536 floats per grid y-row

// Block (64,4) = 4 independent waves; each wave owns 4 output rows (TH=16).
// BARRIER-FREE: per-wave image slice [6 rows][200 floats] staged by width-4
// global_load_lds with compile-time chunk offsets (no per-lane div/clamp);
// per-wave table rows; one per-wave waitcnt fence. f32 conv, r0 epilogue.
#define TW 64
#define WROWS 4
#define TH 16                // 4 waves * 4 rows
#define RSTR 200             // floats per slice row (198 used + 2 pad)

typedef _Float16 h2 __attribute__((ext_vector_type(2)));

__device__ __forceinline__ h2 u2h(unsigned int u) { return __builtin_bit_cast(h2, u); }

// global -> LDS DMA, 4 bytes/lane (r8-proven). dest = uniform base + lane*4.
__device__ __forceinline__ void gload_lds4(const float* g, float* l) {
    auto gp = (const __attribute__((address_space(1))) float*)g;
    auto lp = (__attribute__((address_space(3))) float*)l;
    __builtin_amdgcn_global_load_lds(gp, lp, 4, 0, 0);
}

// 3x3 conv for one output row from rows a,b,c (kh=0,1,2) — r8-verbatim math.
__device__ __forceinline__ void conv3r(const float* a, const float* b, const float* c,
                                       float* acc, const float* wgt,
                                       float bias0, float bias1, float bias2) {
    acc[0] = bias0; acc[1] = bias1; acc[2] = bias2;
    const float* rows[3] = {a, b, c};
    #pragma unroll
    for (int kh = 0; kh < 3; ++kh)
        #pragma unroll
        for (int kw = 0; kw < 3; ++kw)
            #pragma unroll
            for (int ci = 0; ci < 3; ++ci) {
                float v = rows[kh][kw * 3 + ci];
                const float* wb = wgt + ((kh * 3 + kw) * 3 + ci) * 3;
                acc[0] += v * wb[0];
                acc[1] += v * wb[1];
                acc[2] += v * wb[2];
            }
}

__global__ __launch_bounds__(256, 5)
void fused_conv_slice(const float* __restrict__ grid,
                      const float* __restrict__ guide,
                      const float* __restrict__ image,
                      const float* __restrict__ conv_w,
                      const float* __restrict__ conv_b,
                      float* __restrict__ out)
{
    // Per-wave f32 image slice: rows yw0-1 .. yw0+4, cols x0-1 .. x0+64.
    __shared__ float s_img[4][6][RSTR];            // 19200 B
    // f16 y-lerped tables (16 rows x 24 corners), r0 split layout.
    __shared__ uint4 s_t128[TH][3 * GD];           // 6144 B
    __shared__ uint2 s_t64 [TH][3 * GD];           // 3072 B   (28416 B total -> 5 blocks/CU)

    const int tx  = threadIdx.x;   // 0..63 (one wave per tyq)
    const int tyq = threadIdx.y;   // 0..3 (independent wave)
    const int bx  = blockIdx.x;
    const int by  = blockIdx.y;
    const int b   = blockIdx.z;
    const int x0 = bx * TW;
    const int y0 = by * TH;
    const int yw0 = y0 + tyq * WROWS;             // wave's first output row
    const int wr0 = yw0 - 1;                      // wave's first staged input row
    const float* ib = image + b * (H_ * W_ * 3);
    const float* gB = grid + b * (GH * GW * GD * NC);

    // ---- per-wave image staging ----
    const bool edge = (bx == 0) | (bx == (W_ / TW - 1)) |
                      ((by == 0) & (tyq == 0)) | ((by == (H_ / TH - 1)) & (tyq == 3));
    if (!edge) {
        // 6 rows x 4 chunks, dest offsets {0,64,128,134}: chunk 3 overlaps chunk 2
        // on floats 134..191 with IDENTICAL src values (benign double-write, no clamp).
        #pragma unroll
        for (int r = 0; r < 6; ++r) {
            const float* rowbase = ib + ((wr0 + r) * W_ + (x0 - 1)) * 3;
            gload_lds4(rowbase +   0 + tx, &s_img[tyq][r][0]);
            gload_lds4(rowbase +  64 + tx, &s_img[tyq][r][64]);
            gload_lds4(rowbase + 128 + tx, &s_img[tyq][r][128]);
            gload_lds4(rowbase + 134 + tx, &s_img[tyq][r][134]);
        }
    } else {
        // Guarded per-wave reg path with zero padding (border waves only).
        #pragma unroll
        for (int i = 0; i < 7; ++i) {
            int p = i * 64 + tx;                  // px 0..395 (6 rows x 66)
            if (p < 396) {
                int r = p / 66;
                int c = p - r * 66;
                int yy = wr0 + r;
                int xx = x0 - 1 + c;
                float v[3] = {0.f, 0.f, 0.f};
                if (((unsigned)yy < (unsigned)H_) && ((unsigned)xx < (unsigned)W_))
                    __builtin_memcpy(v, ib + (yy * W_ + xx) * 3, 12);
                float* d = &s_img[tyq][r][c * 3];
                d[0] = v[0]; d[1] = v[1]; d[2] = v[2];
            }
        }
    }

    // ---- per-wave table fill: 96 corners (4 rows x 3 cells x 8 z), 2 passes ----
    #pragma unroll
    for (int k = 0; k < 2; ++k) {
        int cid = k * 64 + tx;
        if (cid < WROWS * 24) {
            int rr  = cid / 24;                   // wave-local row 0..3
            int rem = cid - rr * 24;
            int s   = rem >> 3;                   // cell slot 0..2
            int z   = rem & 7;
            float gyf = (yw0 + rr + 0.5f) * (1.0f / 64.0f) - 0.5f;
            float fyf = floorf(gyf);
            float tyw = gyf - fyf;
            int iy  = (int)fyf;
            int yi0 = min(max(iy, 0), GH - 1);
            int yi1 = min(max(iy + 1, 0), GH - 1);
            float wy0 = 1.0f - tyw, wy1 = tyw;
            int cellx = min(max(bx - 1 + s, 0), GW - 1);
            const float4* G0 = (const float4*)(gB + yi0 * YROWF + cellx * CELLF + z * NC);
            const float4* G1 = (const float4*)(gB + yi1 * YROWF + cellx * CELLF + z * NC);
            float4 a0 = G0[0], a1 = G0[1], a2 = G0[2];
            float4 c0 = G1[0], c1 = G1[1], c2 = G1[2];
            h2 p0, p1, p2, p3, p4, p5;           // RTE casts: r0/r8 numerics
            p0.x = (_Float16)(wy0 * a0.x + wy1 * c0.x); p0.y = (_Float16)(wy0 * a0.y + wy1 * c0.y);
            p1.x = (_Float16)(wy0 * a0.z + wy1 * c0.z); p1.y = (_Float16)(wy0 * a0.w + wy1 * c0.w);
            p2.x = (_Float16)(wy0 * a1.x + wy1 * c1.x); p2.y = (_Float16)(wy0 * a1.y + wy1 * c1.y);
            p3.x = (_Float16)(wy0 * a1.z + wy1 * c1.z); p3.y = (_Float16)(wy0 * a1.w + wy1 * c1.w);
            p4.x = (_Float16)(wy0 * a2.x + wy1 * c2.x); p4.y = (_Float16)(wy0 * a2.y + wy1 * c2.y);
            p5.x = (_Float16)(wy0 * a2.z + wy1 * c2.z); p5.y = (_Float16)(wy0 * a2.w + wy1 * c2.w);
            uint4 lo;
            lo.x = __builtin_bit_cast(unsigned int, p0);
            lo.y = __builtin_bit_cast(unsigned int, p1);
            lo.z = __builtin_bit_cast(unsigned int, p2);
            lo.w = __builtin_bit_cast(unsigned int, p3);
            uint2 hi;
            hi.x = __builtin_bit_cast(unsigned int, p4);
            hi.y = __builtin_bit_cast(unsigned int, p5);
            int ci = s * GD + z;
            s_t128[tyq * WROWS + rr][ci] = lo;
            s_t64 [tyq * WROWS + rr][ci] = hi;
        }
    }

    // ---- guide prefetch (4 rows) ----
    const int x = x0 + tx;
    const int guidebase = b * (H_ * W_);
    float g4[4];
    #pragma unroll
    for (int j = 0; j < 4; ++j)
        g4[j] = guide[guidebase + (yw0 + j) * W_ + x];

    // ---- conv weights: uniform reads -> SGPRs ----
    float wgt[81];
    #pragma unroll
    for (int i = 0; i < 81; ++i) wgt[i] = conv_w[i];
    float bias0 = conv_b[0], bias1 = conv_b[1], bias2 = conv_b[2];

    // ---- per-wave fence (r8-proven): drains this wave's DMAs + ds_writes.
    __asm__ __volatile__("s_waitcnt vmcnt(0) lgkmcnt(0)" ::: "memory");
    __builtin_amdgcn_sched_barrier(0);

    // ---- conv: rolling 3-row window over the wave's 6 LDS rows ----
    auto ldr9 = [&](int r, float* d) {
        __builtin_memcpy(d, &s_img[tyq][r][tx * 3], 36);
    };
    float ra[9], rb[9], rc[9];
    float acc4[4][3];
    ldr9(0, ra); ldr9(1, rb); ldr9(2, rc);
    conv3r(ra, rb, rc, acc4[0], wgt, bias0, bias1, bias2);
    ldr9(3, ra);
    conv3r(rb, rc, ra, acc4[1], wgt, bias0, bias1, bias2);
    ldr9(4, rb);
    conv3r(rc, ra, rb, acc4[2], wgt, bias0, bias1, bias2);
    ldr9(5, rc);
    conv3r(ra, rb, rc, acc4[3], wgt, bias0, bias1, bias2);

    // ---- per-thread x-interp setup (r0-verbatim) ----
    float gxf = (x + 0.5f) * (1.0f / 64.0f) - 0.5f;
    float fxf = floorf(gxf);
    float txw = gxf - fxf;
    float wxa = 1.0f - txw, wxb = txw;
    int s0 = (int)fxf - (bx - 1);   // table x-slot of left corner: 0 or 1

    const int outbase = b * (H_ * W_ * 3);

    #pragma unroll
    for (int j = 0; j < 4; ++j) {
        int y = yw0 + j;
        const uint4* T128 = &s_t128[tyq * WROWS + j][0];
        const uint2* T64  = &s_t64 [tyq * WROWS + j][0];

        float gzf = g4[j] * 8.0f - 0.5f;
        float fzf = floorf(gzf);
        float tz = gzf - fzf;
        int iz = (int)fzf;                    // -1..7
        int zb = min(max(iz, 0), GD - 2);     // contiguous z-pair base
        float wA = (iz < 0) ? 1.0f : ((iz > GD - 2) ? 0.0f : (1.0f - tz));
        float wB = 1.0f - wA;

        float m0 = wxa * wA, m1 = wxa * wB, m2 = wxb * wA, m3 = wxb * wB;
        h2 m0h = {(_Float16)m0, (_Float16)m0};
        h2 m1h = {(_Float16)m1, (_Float16)m1};
        h2 m2h = {(_Float16)m2, (_Float16)m2};
        h2 m3h = {(_Float16)m3, (_Float16)m3};

        // corners: A=(s0,zb) B=(s0,zb+1) C=(s0+1,zb) D=(s0+1,zb+1)
        int ci0 = s0 * GD + zb;
        uint4 Alo = T128[ci0];          uint2 Ahi = T64[ci0];
        uint4 Blo = T128[ci0 + 1];      uint2 Bhi = T64[ci0 + 1];
        uint4 Clo = T128[ci0 + GD];     uint2 Chi = T64[ci0 + GD];
        uint4 Dlo = T128[ci0 + GD + 1]; uint2 Dhi = T64[ci0 + GD + 1];

        h2 A[6]  = {u2h(Alo.x), u2h(Alo.y), u2h(Alo.z), u2h(Alo.w), u2h(Ahi.x), u2h(Ahi.y)};
        h2 Bv[6] = {u2h(Blo.x), u2h(Blo.y), u2h(Blo.z), u2h(Blo.w), u2h(Bhi.x), u2h(Bhi.y)};
        h2 Cv[6] = {u2h(Clo.x), u2h(Clo.y), u2h(Clo.z), u2h(Clo.w), u2h(Chi.x), u2h(Chi.y)};
        h2 Dv[6] = {u2h(Dlo.x), u2h(Dlo.y), u2h(Dlo.z), u2h(Dlo.w), u2h(Dhi.x), u2h(Dhi.y)};

        // packed-f16 4-corner lerp
        h2 c[6];
        #pragma unroll
        for (int k = 0; k < 6; ++k)
            c[k] = __builtin_elementwise_fma(A[k], m0h,
                   __builtin_elementwise_fma(Bv[k], m1h,
                   __builtin_elementwise_fma(Cv[k], m2h, Dv[k] * m3h)));

        // apply: out_o = c[2o]·{a0,a1} + c[2o+1]·{a2,1}  (fdot2, f32 accumulate)
        float a0 = acc4[j][0], a1 = acc4[j][1], a2 = acc4[j][2];
        h2 q01 = {(_Float16)a0, (_Float16)a1};
        h2 q21 = {(_Float16)a2, (_Float16)1.0f};

        int oidx = outbase + (y * W_ + x) * 3;
        #pragma unroll
        for (int o3 = 0; o3 < 3; ++o3) {
            float t = __builtin_amdgcn_fdot2(c[2 * o3 + 1], q21, 0.0f, false);
            out[oidx + o3] = __builtin_amdgcn_fdot2(c[2 * o3], q01, t, false);
        }
    }
}

extern "C" void kernel_launch(void* const* d_in, const int* in_sizes, int n_in,
                              void* d_out, int out_size, void* d_ws, size_t ws_size,
                              hipStream_t stream) {
    const float* grid   = (const float*)d_in[0];
    const float* guide  = (const float*)d_in[1];
    const float* image  = (const float*)d_in[2];
    const float* conv_w = (const float*)d_in[3];
    const float* conv_b = (const float*)d_in[4];
    float* out = (float*)d_out;

    dim3 block(64, 4, 1);
    dim3 grid_dim(W_ / TW, H_ / TH, B_);  // (16, 64, 4)
    fused_conv_slice<<<grid_dim, block, 0, stream>>>(grid, guide, image, conv_w, conv_b, out);
}